// Round 10
// baseline (168.065 us; speedup 1.0000x reference)
//
#include <hip/hip_runtime.h>
#include <cstdint>
#include <cstddef>

// ---------------------------------------------------------------------------
// LSTM cell, B=8192, D=H=512, fp32 in/out.
// pre = [x|h] @ Wstack^T + bias ; gates -> c_t, h_t fused in GEMM epilogue.
// Round 13: champion r12 with the K-loop's MFMA shape swapped to
// mfma_f32_32x32x16_bf16 (the faster matrix unit: 2382 vs 2075 TF ubench;
// 16 MFMA x 8.07cyc = 129 cyc/K-step vs 32 x 4.85 = 155). Same ds_read
// volume and the same 8-lanes-per-chunk swizzled distribution (operand
// layout: row = lane&31, k-group = lane>>5, by analogy with the proven
// 16x16 row=lane&15/kgrp=lane>>4). Epilogue uses the verified 32x32 C/D
// mapping col=lane&31, row=(reg&3)+8*(reg>>2)+4*(lane>>5) (m74/m101).
// Everything else (staging, swizzle, barriers, pack v2, epilogue math)
// is byte-identical to the r12 champion (164.8us total, GEMM 47.2us).
// ---------------------------------------------------------------------------

typedef __attribute__((ext_vector_type(8))) short short8;     // 8 bf16
typedef __attribute__((ext_vector_type(16))) float floatx16;  // 32x32 acc

#define AS1(p) ((const __attribute__((address_space(1))) void*)(p))
#define AS3(p) ((__attribute__((address_space(3))) void*)(p))

__device__ __forceinline__ unsigned short f2bf(float f) {
  union { float f; unsigned u; } v; v.f = f;
  unsigned u = v.u;
  return (unsigned short)((u + 0x7fffu + ((u >> 16) & 1u)) >> 16);  // RNE
}

// --------------------------- pack everything -------------------------------
// A[b][k] = k<512 ? x[b][k] : h[b][k-512]                  (8192x1024 bf16)
// B[n][k], n = hh*4 + g (h-interleaved gates f,i,g,o), k<512 -> Wx else Wh;
// bias[n] = bx+bh written by the k==0 thread.  8 elems/thread (r12-proven).
struct PackArgs {
  const float* x; const float* h;
  const float* wx[4]; const float* wh[4];
  const float* bx[4]; const float* bh[4];
  unsigned short* A; unsigned short* B; float* bias;
};

__global__ __launch_bounds__(256) void pack_all_kernel(PackArgs P) {
  const int gid = blockIdx.x * 256 + threadIdx.x;
  const float* src;
  unsigned short* dst;
  if (gid < 1048576) {                    // ---- A: 8192 rows x 128 chunks ----
    int b = gid >> 7, k = (gid & 127) * 8;
    src = (k < 512) ? (P.x + b * 512 + k) : (P.h + b * 512 + (k - 512));
    dst = P.A + ((size_t)b << 10) + k;
  } else {                                // ---- B: 2048 rows x 128 chunks ----
    int g2 = gid - 1048576;
    int n = g2 >> 7, k = (g2 & 127) * 8;
    int g = n & 3, hh = n >> 2;           // h-interleaved layout
    src = (k < 512) ? (P.wx[g] + hh * 512 + k) : (P.wh[g] + hh * 512 + (k - 512));
    dst = P.B + ((size_t)n << 10) + k;
    if (k == 0) P.bias[n] = P.bx[g][hh] + P.bh[g][hh];
  }
  float4 v0 = ((const float4*)src)[0];
  float4 v1 = ((const float4*)src)[1];
  union { unsigned short us[8]; short8 s; } o;
  o.us[0] = f2bf(v0.x); o.us[1] = f2bf(v0.y);
  o.us[2] = f2bf(v0.z); o.us[3] = f2bf(v0.w);
  o.us[4] = f2bf(v1.x); o.us[5] = f2bf(v1.y);
  o.us[6] = f2bf(v1.z); o.us[7] = f2bf(v1.w);
  *(short8*)dst = o.s;
}

// --------------------------- fused GEMM + LSTM epilogue --------------------
// Grid (32,16): tile = 256 batch x 128 cols (32 hidden x 4 gates). K=1024,
// BK=64. 512 threads = 8 waves; wave tile 64x64 = 2x2 of 32x32 MFMA tiles.
// LDS: As 32KB @ [0,32768), Bs 16KB @ [32768,49152); epilogue overlays As.
__global__ __launch_bounds__(512, 4)
void lstm_gemm_kernel(const unsigned short* __restrict__ A,   // [8192][1024]
                      const unsigned short* __restrict__ B,   // [2048][1024]
                      const float* __restrict__ bias,         // [2048]
                      const float* __restrict__ c_prev,       // [8192][512]
                      float* __restrict__ h_out,              // [8192][512]
                      float* __restrict__ c_out) {            // [8192][512]
  __shared__ __align__(16) char smem[49152];
  __shared__ __align__(16) float biasS[128];

  const int tid  = threadIdx.x;
  const int lane = tid & 63;
  const int w    = tid >> 6;        // wave 0..7
  const int row32 = lane & 31;      // 32x32 operand row
  const int kgrp  = lane >> 5;      // k-group (k = kgrp*8 .. +7)
  const int c7    = lane & 7;       // swizzle key (row&7 == lane&7)
  const int m0   = blockIdx.x * 256;
  const int n0   = blockIdx.y * 128;    // = 4*h0
  const int h0   = blockIdx.y * 32;

  if (tid < 128) biasS[tid] = bias[n0 + tid];   // contiguous (h-interleave)

  // staging: thread covers tile-row r = j*64 + (tid>>3), 16B chunk (tid&7);
  // global chunk XOR-swizzled by row&7 so ds_read_b128 frags are conflict-free
  const int srow = tid >> 3;        // 0..63
  const int cl   = tid & 7;
  const int cg   = cl ^ (srow & 7);

  floatx16 acc[2][2];
#pragma unroll
  for (int i = 0; i < 2; ++i)
#pragma unroll
    for (int j = 0; j < 2; ++j)
#pragma unroll
      for (int e = 0; e < 16; ++e) acc[i][j][e] = 0.f;

  const int wm = (w >> 1) * 64;     // wave M offset in tile (0,64,128,192)
  const int wn = (w & 1) * 64;      // wave N offset (0 or 64)

  const char* Ag = (const char*)A;
  const char* Bg = (const char*)B;

  for (int kt = 0; kt < 16; ++kt) {
    __syncthreads();                // prior LDS reads done
    const int kb = kt * 128;        // byte offset into 2048-B rows
#pragma unroll
    for (int j = 0; j < 4; ++j) {   // A: 256 rows
      int r = j * 64 + srow;        // tile row 0..255 (r&7 == srow&7)
      __builtin_amdgcn_global_load_lds(
          AS1(Ag + (size_t)(m0 + r) * 2048 + kb + cg * 16),
          AS3(smem + r * 128 + cl * 16), 16, 0, 0);
    }
#pragma unroll
    for (int j = 0; j < 2; ++j) {   // B: 128 rows (h-interleaved)
      int r = j * 64 + srow;        // tile row 0..127
      __builtin_amdgcn_global_load_lds(
          AS1(Bg + (size_t)(n0 + r) * 2048 + kb + cg * 16),
          AS3(smem + 32768 + r * 128 + cl * 16), 16, 0, 0);
    }
    __syncthreads();                // drains vmcnt(0)

    // 4 k-slices of 16; lane reads global chunk 2*ks+kgrp of its row,
    // stored at (2*ks+kgrp)^c7 (row&7 == c7 for all frag rows).
#pragma unroll
    for (int ks = 0; ks < 4; ++ks) {
      const int off = ((2 * ks + kgrp) ^ c7) * 16;
      short8 af[2], bfr[2];
#pragma unroll
      for (int mt = 0; mt < 2; ++mt)
        af[mt] = *(const short8*)(smem + (wm + mt * 32 + row32) * 128 + off);
#pragma unroll
      for (int nt = 0; nt < 2; ++nt)
        bfr[nt] = *(const short8*)(smem + 32768 + (wn + nt * 32 + row32) * 128 + off);
#pragma unroll
      for (int mt = 0; mt < 2; ++mt)
#pragma unroll
        for (int nt = 0; nt < 2; ++nt)
          acc[mt][nt] = __builtin_amdgcn_mfma_f32_32x32x16_bf16(
              af[mt], bfr[nt], acc[mt][nt], 0, 0, 0);
    }
  }

  // ------------------- fused epilogue (4 rounds of 64 M-rows) --------------
  __syncthreads();
  float* ep = (float*)smem;         // [64][132] padded, overlays As
#pragma unroll
  for (int rd = 0; rd < 4; ++rd) {
    // c_prev hoisted: HBM latency hides under ep writes + barrier
    float cp[4];
#pragma unroll
    for (int j = 0; j < 4; ++j) {
      int idx  = j * 512 + tid;     // 0..2047
      int mloc = idx >> 5;
      int hh   = idx & 31;
      cp[j] = c_prev[(m0 + rd * 64 + mloc) * 512 + h0 + hh];
    }
    if ((w >> 1) == rd) {           // the 2 waves with wm == rd*64
      // 32x32 C/D layout: col = lane&31, row = (reg&3)+8*(reg>>2)+4*(lane>>5)
#pragma unroll
      for (int mt = 0; mt < 2; ++mt)
#pragma unroll
        for (int nt = 0; nt < 2; ++nt) {
          int cc = wn + nt * 32 + row32;                // col 0..127
#pragma unroll
          for (int reg = 0; reg < 16; ++reg) {
            int rr = mt * 32 + (reg & 3) + 8 * (reg >> 2) + 4 * kgrp;  // 0..63
            ep[rr * 132 + cc] = acc[mt][nt][reg];
          }
        }
    }
    __syncthreads();
#pragma unroll
    for (int j = 0; j < 4; ++j) {
      int idx  = j * 512 + tid;     // 0..2047
      int mloc = idx >> 5;
      int hh   = idx & 31;
      // one aligned float4 = (f,i,g,o) pre-activations for this (m,h)
      float4 pre = *(const float4*)(ep + mloc * 132 + hh * 4);
      float4 bb  = *(const float4*)(biasS + hh * 4);
      float pf = pre.x + bb.x;
      float pi = pre.y + bb.y;
      float pg = pre.z + bb.z;
      float po = pre.w + bb.w;
      float fg = 1.f / (1.f + __expf(-pf));
      float ig = 1.f / (1.f + __expf(-pi));
      float gg = 1.f - 2.f / (1.f + __expf(2.f * pg));
      float og = 1.f / (1.f + __expf(-po));
      float cv = fg * cp[j] + ig * gg;
      float th = 1.f - 2.f / (1.f + __expf(2.f * cv));
      int m  = m0 + rd * 64 + mloc;
      int hg = h0 + hh;
      h_out[m * 512 + hg] = og * th;
      c_out[m * 512 + hg] = cv;
    }
    __syncthreads();
  }
}

// ---------------------------------------------------------------------------
extern "C" void kernel_launch(void* const* d_in, const int* in_sizes, int n_in,
                              void* d_out, int out_size, void* d_ws, size_t ws_size,
                              hipStream_t stream) {
  // workspace: A_bf16 (16 MiB) | B_bf16 (4 MiB) | bias (8 KiB)
  char* ws = (char*)d_ws;
  unsigned short* Abf = (unsigned short*)ws;
  unsigned short* Bbf = (unsigned short*)(ws + (size_t)16777216);
  float* bias = (float*)(ws + (size_t)16777216 + 4194304);

  float* hout = (float*)d_out;
  float* cout = hout + (size_t)8192 * 512;

  PackArgs P;
  P.x = (const float*)d_in[0];
  P.h = (const float*)d_in[1];
  // gate order: 0=f, 1=i, 2=g(cell), 3=o
  P.wx[0] = (const float*)d_in[3];  P.bx[0] = (const float*)d_in[4];
  P.wh[0] = (const float*)d_in[5];  P.bh[0] = (const float*)d_in[6];
  P.wx[1] = (const float*)d_in[7];  P.bx[1] = (const float*)d_in[8];
  P.wh[1] = (const float*)d_in[9];  P.bh[1] = (const float*)d_in[10];
  P.wx[2] = (const float*)d_in[11]; P.bx[2] = (const float*)d_in[12];
  P.wh[2] = (const float*)d_in[13]; P.bh[2] = (const float*)d_in[14];
  P.wx[3] = (const float*)d_in[15]; P.bx[3] = (const float*)d_in[16];
  P.wh[3] = (const float*)d_in[17]; P.bh[3] = (const float*)d_in[18];
  P.A = Abf; P.B = Bbf; P.bias = bias;

  // A: 1048576 threads + B: 262144 threads = 5120 blocks of 256
  pack_all_kernel<<<5120, 256, 0, stream>>>(P);

  const float* c = (const float*)d_in[2];
  dim3 grid(32, 16);
  lstm_gemm_kernel<<<grid, 512, 0, stream>>>(Abf, Bbf, bias, c, hout, cout);
}